// Round 1
// baseline (100.203 us; speedup 1.0000x reference)
//
#include <hip/hip_runtime.h>

// Encode 11x11 hex boards -> (B, 27, 12, 12) one-hot pattern tensor.
// Memory-bound: 509.6 MB output stream. One block per board.

__global__ __launch_bounds__(256) void hex_encode_kernel(
    const float* __restrict__ boards, float* __restrict__ out)
{
    __shared__ float sP[169];                          // 13x13 padded board
    __shared__ __align__(16) unsigned short sMask[144]; // per-cell 9-bit match mask

    const int tid = threadIdx.x;
    const int b = blockIdx.x;
    const float* board = boards + (size_t)b * 121;

    // Build padded P (13x13): interior = board, top/bottom edges = +1,
    // left/right edges = -1, corners = 0.
    if (tid < 169) {
        int pr = tid / 13, pc = tid % 13;
        bool ir = (pr >= 1) & (pr <= 11);
        bool jr = (pc >= 1) & (pc <= 11);
        float v;
        if (ir & jr)  v = board[(pr - 1) * 11 + (pc - 1)];
        else if (jr)  v = 1.0f;    // pr == 0 or 12
        else if (ir)  v = -1.0f;   // pc == 0 or 12
        else          v = 0.0f;    // corners
        sP[tid] = v;
    }
    __syncthreads();

    // Per-cell mask: 3 fields of 3 bits, one-hot on (value+1), or 0b111 at
    // the three corner-override cells (exactly where a corner of P is read).
    if (tid < 144) {
        int r = tid / 12, c = tid % 12;
        int i0 = (int)sP[r * 13 + c] + 1;        // a0 = P[r][c]
        int i1 = (int)sP[r * 13 + c + 1] + 1;    // a1 = P[r][c+1]
        int i2 = (int)sP[(r + 1) * 13 + c] + 1;  // a2 = P[r+1][c]
        unsigned m0 = (tid == 0)   ? 7u : (1u << i0);   // eq0 override at (0,0)
        unsigned m1 = (tid == 11)  ? 7u : (1u << i1);   // eq1 override at (0,11)
        unsigned m2 = (tid == 132) ? 7u : (1u << i2);   // eq2 override at (11,0)
        sMask[tid] = (unsigned short)(m0 | (m1 << 3) | (m2 << 6));
    }
    __syncthreads();

    // Write 3888 floats = 972 float4 per board, coalesced.
    float* outb = out + (size_t)b * 3888;
    const unsigned long long* mask64 = (const unsigned long long*)sMask;
    #pragma unroll
    for (int it = 0; it < 4; ++it) {
        int idx = tid + it * 256;          // float4 index in [0, 972)
        if (idx < 972) {
            int p = idx / 36;              // pattern 0..26 (144 elems = 36 float4 per p)
            int cell4 = idx - p * 36;      // group of 4 cells within the 144
            int v0 = p / 9, v1 = (p / 3) % 3, v2 = p % 3;
            unsigned need = (1u << v0) | (1u << (3 + v1)) | (1u << (6 + v2));
            unsigned long long m4 = mask64[cell4];  // 4 cells' masks, one b64 read
            float4 o;
            o.x = (((unsigned)(m4)       & need) == need) ? 1.0f : 0.0f;
            o.y = (((unsigned)(m4 >> 16) & need) == need) ? 1.0f : 0.0f;
            o.z = (((unsigned)(m4 >> 32) & need) == need) ? 1.0f : 0.0f;
            o.w = (((unsigned)(m4 >> 48) & need) == need) ? 1.0f : 0.0f;
            *(float4*)(outb + idx * 4) = o;
        }
    }
}

extern "C" void kernel_launch(void* const* d_in, const int* in_sizes, int n_in,
                              void* d_out, int out_size, void* d_ws, size_t ws_size,
                              hipStream_t stream) {
    const float* boards = (const float*)d_in[0];
    float* out = (float*)d_out;
    hex_encode_kernel<<<32768, 256, 0, stream>>>(boards, out);
}